// Round 12
// baseline (7618.317 us; speedup 1.0000x reference)
//
#include <hip/hip_runtime.h>
#include <hip/hip_bf16.h>

#define B_  64
#define T_  12
#define N_  325
#define DIN 2
#define H_  128
#define BN  (B_*N_)    // 20800
#define DPITCH 384     // padded node pitch (k-extent) for transposed/support buffers
#define AROWS 384      // padded m-rows per support matrix

typedef __hip_bfloat16 bf16;
typedef unsigned short u16;
typedef __attribute__((ext_vector_type(8))) short short8;
typedef __attribute__((ext_vector_type(4))) float f32x4;

__device__ __forceinline__ float b2f(bf16 v){ return __bfloat162float(v); }
__device__ __forceinline__ u16 f2b(float f){
    __hip_bfloat16 h = __float2bfloat16(f);
    return *reinterpret_cast<u16*>(&h);
}

// async global->LDS, 16B per lane; dest = base + lane*16 (wave-uniform base)
__device__ __forceinline__ void gl_lds16(const u16* g, u16* l){
    __builtin_amdgcn_global_load_lds(
        (const __attribute__((address_space(1))) unsigned int*)g,
        (__attribute__((address_space(3))) unsigned int*)l, 16, 0, 0);
}

// ---------------------------------------------------------------------------
// Dtype sniffer + one-shot fp32 conversion of all float inputs
// ---------------------------------------------------------------------------
__global__ void sniff(const void* __restrict__ sup, int* __restrict__ flag){
    if (threadIdx.x == 0 && blockIdx.x == 0){
        float sb = 0.f, sf = 0.f;
        for (int n = 0; n < N_; ++n){
            sb += b2f(((const bf16*)sup)[n]);
            sf += ((const float*)sup)[n];
        }
        float db = fabsf(sb - 1.f), df = fabsf(sf - 1.f);
        *flag = (db < df) ? 1 : 0;
    }
}

struct CvtArgs {
    const void* src[20];
    float*      dst[20];
    int         n[20];
};

__global__ void cvt_all(CvtArgs a, const int* __restrict__ flag){
    int ii = blockIdx.y;
    int i  = blockIdx.x*256 + threadIdx.x;
    int n  = a.n[ii];
    if (i >= n) return;
    if (*flag) a.dst[ii][i] = b2f(((const bf16*)a.src[ii])[i]);
    else       a.dst[ii][i] = ((const float*)a.src[ii])[i];
}

// ---------------------------------------------------------------------------
// msq[0]=S0, msq[1]=S0@S0, msq[2]=S1, msq[3]=S1@S1   (fp32)
// ---------------------------------------------------------------------------
__global__ void support_prep(const float* __restrict__ sup, float* __restrict__ msq){
    int s = blockIdx.z;
    int m = blockIdx.y*16 + threadIdx.y;
    int n = blockIdx.x*16 + threadIdx.x;
    __shared__ float As[16][17], Bs[16][17];
    const float* S = sup + (size_t)s*N_*N_;
    float acc = 0.f;
    for (int j0 = 0; j0 < N_; j0 += 16){
        As[threadIdx.y][threadIdx.x] = (m < N_ && j0+threadIdx.x < N_) ? S[m*N_ + j0+threadIdx.x] : 0.f;
        Bs[threadIdx.y][threadIdx.x] = (j0+threadIdx.y < N_ && n < N_) ? S[(j0+threadIdx.y)*N_ + n] : 0.f;
        __syncthreads();
        #pragma unroll
        for (int jj=0; jj<16; ++jj) acc += As[threadIdx.y][jj]*Bs[jj][threadIdx.x];
        __syncthreads();
    }
    if (m < N_ && n < N_){
        msq[(size_t)(2*s  )*N_*N_ + m*N_ + n] = S[m*N_ + n];
        msq[(size_t)(2*s+1)*N_*N_ + m*N_ + n] = acc;
    }
}

// asq[k][m<384][col<384] = bf16(msq[k][m][col]) zero-padded in rows AND cols
__global__ void asq_prep(const float* __restrict__ msq, u16* __restrict__ asq){
    int idx = blockIdx.x*256 + threadIdx.x;
    int total = 4*AROWS*DPITCH;
    if (idx >= total) return;
    int col = idx % DPITCH;
    int rm  = idx / DPITCH;
    int m   = rm % AROWS;
    int k   = rm / AROWS;
    asq[idx] = (m < N_ && col < N_) ? f2b(msq[((size_t)k*N_ + m)*N_ + col]) : 0;
}

// ---------------------------------------------------------------------------
// Weight transpose: W[KC][Nout] fp32 -> Wt[Nout][KCpad] bf16 (k zero-padded)
// ---------------------------------------------------------------------------
__global__ __launch_bounds__(256) void wtrans(const float* __restrict__ W, u16* __restrict__ Wt,
                                              int KC, int Nout, int KCpad){
    int k0 = blockIdx.x*64, c0 = blockIdx.y*64;
    int tid = threadIdx.x;
    __shared__ u16 T[64][72];
    #pragma unroll
    for (int it=0; it<2; ++it){
        int lin = it*256 + tid;
        int kl = lin >> 3, seg = lin & 7;
        int gk = k0 + kl, gc = c0 + seg*8;
        u16 tmp[8];
        #pragma unroll
        for (int e=0;e<8;++e) tmp[e] = (gk < KC) ? f2b(W[(size_t)gk*Nout + gc + e]) : 0;
        *(uint4*)&T[kl][seg*8] = *(const uint4*)tmp;
    }
    __syncthreads();
    #pragma unroll
    for (int it=0; it<2; ++it){
        int lin = it*256 + tid;
        int cl = lin >> 3, seg = lin & 7;
        u16 tmp[8];
        #pragma unroll
        for (int j=0;j<8;++j) tmp[j] = T[seg*8+j][cl];
        *(uint4*)(Wt + (size_t)(c0+cl)*KCpad + k0 + seg*8) = *(const uint4*)tmp;
    }
}

// ---------------------------------------------------------------------------
// fill_t: build F slot0 = [x|h] (bf16, row-major) AND Ft = transpose (c-major,
// node pitch DPITCH, zero-padded). grid (DPITCH/64, Cpad/64, Bc)
// ---------------------------------------------------------------------------
__global__ __launch_bounds__(256) void fill_t(u16* __restrict__ F, u16* __restrict__ Ft,
                                              int C, int KC, int Cpad, int Din, int b0,
                                              const float* __restrict__ x, long xbs,
                                              const float* __restrict__ h){
    int bl = blockIdx.z;
    int bg = b0 + bl;
    int n0 = blockIdx.x*64, c0 = blockIdx.y*64;
    int tid = threadIdx.x;
    __shared__ u16 T[64][72];
    #pragma unroll
    for (int it=0; it<2; ++it){
        int lin = it*256 + tid;
        int nl = lin >> 3, seg = lin & 7;
        int gn = n0 + nl;
        u16 tmp[8];
        #pragma unroll
        for (int e=0;e<8;++e){
            int c = c0 + seg*8 + e;
            float v = 0.f;
            if (gn < N_ && c < C)
                v = (c < Din) ? x[(size_t)bg*xbs + (size_t)gn*Din + c]
                              : h[((size_t)bg*N_ + gn)*H_ + (c - Din)];
            tmp[e] = f2b(v);
        }
        *(uint4*)&T[nl][seg*8] = *(const uint4*)tmp;
        if (gn < N_){
            int cbase = c0 + seg*8;
            u16* dst = F + ((size_t)bl*N_ + gn)*KC + cbase;
            if (cbase + 7 < C){
                *(uint4*)dst = *(const uint4*)tmp;
            } else {
                #pragma unroll
                for (int e=0;e<8;++e) if (cbase + e < C) dst[e] = tmp[e];
            }
        }
    }
    __syncthreads();
    #pragma unroll
    for (int it=0; it<2; ++it){
        int lin = it*256 + tid;
        int cl = lin >> 3, seg = lin & 7;
        u16 tmp[8];
        #pragma unroll
        for (int j=0;j<8;++j) tmp[j] = T[seg*8+j][cl];
        *(uint4*)(Ft + (size_t)bl*Cpad*DPITCH + (size_t)(c0+cl)*DPITCH + n0 + seg*8)
            = *(const uint4*)tmp;
    }
}

// ---------------------------------------------------------------------------
// rh_fill: F[slot0 h-part] = Ft[h-rows] = bf16(r * h)
// ---------------------------------------------------------------------------
__global__ void rh_fill(u16* __restrict__ F, u16* __restrict__ Ft,
                        int KC, int Cpad, int Din, int b0,
                        const float* __restrict__ zr, const float* __restrict__ h){
    int idx = blockIdx.x*256 + threadIdx.x;
    int j   = idx & 127;
    int bnl = idx >> 7;          // grid sized exactly Bc*N_*128/256
    int bl  = bnl / N_;
    int n   = bnl % N_;
    float r  = zr[(size_t)bnl*256 + 128 + j];
    float hv = h[((size_t)b0*N_ + bnl)*128 + j];
    u16 v = f2b(r * hv);
    F[(size_t)bnl*KC + Din + j] = v;
    Ft[((size_t)bl*Cpad + Din + j)*DPITCH + n] = v;
}

// ---------------------------------------------------------------------------
// MFMA diffusion, async staging + swizzle (R8 geometry: 128m x 64c per block).
// 1-D grid with XCD-pinned decode: the 12 blocks sharing one (bl, c-tile) B
// tile (3 m-tiles x 4 supports) are spaced 8 apart -> same XCD -> L2 reuse.
//   F[bl, m, (k+1)C + coff + c] = sum_n Sk[m,n] * Ft[bl, coff+c, n]
// ---------------------------------------------------------------------------
__global__ __launch_bounds__(256) void diffuse_mfma(u16* __restrict__ F,
                                                    const u16* __restrict__ Ft,
                                                    const u16* __restrict__ asq,
                                                    int C, int KC, int Cpad, int coff,
                                                    int ctiles, int T){
    int i   = blockIdx.x;
    int xcd = i & 7;
    int m8  = i >> 3;
    int tg  = m8 / 12;
    int s   = m8 % 12;
    int t   = tg * 8 + xcd;
    if (t >= T) return;                 // block-uniform, before any barrier
    int bl = t / ctiles;
    int cb = t % ctiles;
    int y  = s % 3;
    int k  = s / 3;

    const u16* A    = asq + (size_t)k*AROWS*DPITCH;
    const u16* Bt_g = Ft + ((size_t)bl*Cpad + coff)*DPITCH;
    u16*       Cm   = F + (size_t)bl*N_*KC + (size_t)(k+1)*C + coff;

    int m0 = y * 128;
    int c0 = cb * 64;
    int tid = threadIdx.x;
    int wv = tid >> 6, lane = tid & 63, l15 = lane & 15, quad = lane >> 4;
    int lr = lane >> 3, ls = lane & 7;

    __shared__ u16 As[128*64];
    __shared__ u16 Bs[64*64];

    f32x4 acc[2][4];
    #pragma unroll
    for (int i2=0;i2<2;++i2)
        #pragma unroll
        for (int j=0;j<4;++j) acc[i2][j] = (f32x4){0.f,0.f,0.f,0.f};

    for (int k0 = 0; k0 < N_; k0 += 64){
        #pragma unroll
        for (int j=0;j<4;++j){
            int row = wv*32 + j*8 + lr;
            int seg = ls ^ lr;
            gl_lds16(A + (size_t)(m0+row)*DPITCH + k0 + seg*8, &As[(wv*32 + j*8)*64]);
        }
        #pragma unroll
        for (int j=0;j<2;++j){
            int row = wv*16 + j*8 + lr;
            int seg = ls ^ lr;
            gl_lds16(Bt_g + (size_t)(c0+row)*DPITCH + k0 + seg*8, &Bs[(wv*16 + j*8)*64]);
        }
        __syncthreads();
        #pragma unroll
        for (int ks = 0; ks < 64; ks += 32){
            int sw = (((ks>>3) + quad) ^ (l15 & 7)) << 3;
            short8 a0 = *(const short8*)&As[(wv*32      + l15)*64 + sw];
            short8 a1 = *(const short8*)&As[(wv*32 + 16 + l15)*64 + sw];
            short8 b0 = *(const short8*)&Bs[(     l15)*64 + sw];
            short8 b1 = *(const short8*)&Bs[(16 + l15)*64 + sw];
            short8 b2 = *(const short8*)&Bs[(32 + l15)*64 + sw];
            short8 b3 = *(const short8*)&Bs[(48 + l15)*64 + sw];
            acc[0][0] = __builtin_amdgcn_mfma_f32_16x16x32_bf16(a0,b0,acc[0][0],0,0,0);
            acc[0][1] = __builtin_amdgcn_mfma_f32_16x16x32_bf16(a0,b1,acc[0][1],0,0,0);
            acc[0][2] = __builtin_amdgcn_mfma_f32_16x16x32_bf16(a0,b2,acc[0][2],0,0,0);
            acc[0][3] = __builtin_amdgcn_mfma_f32_16x16x32_bf16(a0,b3,acc[0][3],0,0,0);
            acc[1][0] = __builtin_amdgcn_mfma_f32_16x16x32_bf16(a1,b0,acc[1][0],0,0,0);
            acc[1][1] = __builtin_amdgcn_mfma_f32_16x16x32_bf16(a1,b1,acc[1][1],0,0,0);
            acc[1][2] = __builtin_amdgcn_mfma_f32_16x16x32_bf16(a1,b2,acc[1][2],0,0,0);
            acc[1][3] = __builtin_amdgcn_mfma_f32_16x16x32_bf16(a1,b3,acc[1][3],0,0,0);
        }
        __syncthreads();
    }
    #pragma unroll
    for (int i2=0;i2<2;++i2){
        #pragma unroll
        for (int j=0;j<4;++j){
            int c = c0 + j*16 + l15;
            #pragma unroll
            for (int r=0;r<4;++r){
                int m = m0 + wv*32 + i2*16 + quad*4 + r;
                if (m < N_ && coff + c < C) Cm[(size_t)m*KC + c] = f2b(acc[i2][j][r]);
            }
        }
    }
}

// ---------------------------------------------------------------------------
// MFMA GEMM + fused epilogue, async staging + swizzle. Tile 128m x 128c:
// 32 KB staged per K-tile feeds 32 MFMA (65 FLOP/byte vs 44 at 64c) — A (F)
// traffic halved. 1-D grid, XCD-pinned: c-blocks sharing one r-tile's F rows
// spaced 8 apart -> same XCD L2.
// MODE 0: zr = sigmoid(out) (Nout=256, ct=2). MODE 1: GRU update (ct=1).
// ---------------------------------------------------------------------------
template<int MODE>
__global__ __launch_bounds__(256) void gemm_mfma(const u16* __restrict__ Fb, int KC,
                                                 int rows,
                                                 const u16* __restrict__ Wt, int KCpad,
                                                 const float* __restrict__ bias,
                                                 float* __restrict__ zr,
                                                 float* __restrict__ hb,
                                                 int gy, int ct){
    int i   = blockIdx.x;
    int xcd = i & 7;
    int q   = i >> 3;
    int cb  = q % ct;
    int rt  = (q / ct) * 8 + xcd;
    if (rt >= gy) return;               // block-uniform, before any barrier
    int r0 = rt * 128;
    int c0 = cb * 128;
    int tid = threadIdx.x;
    int wv = tid >> 6, lane = tid & 63, l15 = lane & 15, quad = lane >> 4;
    int lr = lane >> 3, ls = lane & 7;

    __shared__ u16 As[128*64];   // 16 KB
    __shared__ u16 Bs[128*64];   // 16 KB

    f32x4 acc[2][8];
    #pragma unroll
    for (int i2=0;i2<2;++i2)
        #pragma unroll
        for (int j=0;j<8;++j) acc[i2][j] = (f32x4){0.f,0.f,0.f,0.f};

    for (int k0 = 0; k0 < KCpad; k0 += 64){
        if (k0 + 64 <= KC){
            #pragma unroll
            for (int j=0;j<4;++j){
                int row = wv*32 + j*8 + lr;
                int seg = ls ^ lr;
                gl_lds16(Fb + (size_t)(r0+row)*KC + k0 + seg*8, &As[(wv*32 + j*8)*64]);
            }
        } else {
            // K tail: guarded VGPR staging into the same swizzled layout
            #pragma unroll
            for (int it=0; it<4; ++it){
                int lin = it*256 + tid;
                int row = lin >> 3, sp = lin & 7;
                int seg = sp ^ (row & 7);
                int gr = r0 + row, gk = k0 + seg*8;
                u16 tmp[8];
                #pragma unroll
                for (int e=0;e<8;++e)
                    tmp[e] = (gk+e < KC) ? Fb[(size_t)gr*KC + gk+e] : (u16)0;
                *(uint4*)&As[row*64 + sp*8] = *(const uint4*)tmp;
            }
        }
        #pragma unroll
        for (int j=0;j<4;++j){
            int row = wv*32 + j*8 + lr;
            int seg = ls ^ lr;
            gl_lds16(Wt + (size_t)(c0+row)*KCpad + k0 + seg*8, &Bs[(wv*32 + j*8)*64]);
        }
        __syncthreads();
        #pragma unroll
        for (int ks = 0; ks < 64; ks += 32){
            int sw = (((ks>>3) + quad) ^ (l15 & 7)) << 3;
            short8 a0 = *(const short8*)&As[(wv*32      + l15)*64 + sw];
            short8 a1 = *(const short8*)&As[(wv*32 + 16 + l15)*64 + sw];
            #pragma unroll
            for (int j=0;j<8;++j){
                short8 b = *(const short8*)&Bs[(j*16 + l15)*64 + sw];
                acc[0][j] = __builtin_amdgcn_mfma_f32_16x16x32_bf16(a0,b,acc[0][j],0,0,0);
                acc[1][j] = __builtin_amdgcn_mfma_f32_16x16x32_bf16(a1,b,acc[1][j],0,0,0);
            }
        }
        __syncthreads();
    }
    #pragma unroll
    for (int i2=0;i2<2;++i2){
        #pragma unroll
        for (int j=0;j<8;++j){
            int c = c0 + j*16 + l15;
            #pragma unroll
            for (int r=0;r<4;++r){
                int gr = r0 + wv*32 + i2*16 + quad*4 + r;
                if (gr >= rows) continue;
                float v = acc[i2][j][r] + bias[c];
                if (MODE == 0){
                    v = 1.f/(1.f + __expf(-v));
                    zr[(size_t)gr*256 + c] = v;
                } else {
                    float hc   = tanhf(v);
                    float z    = zr[(size_t)gr*256 + c];
                    float hold = hb[(size_t)gr*128 + c];
                    hb[(size_t)gr*128 + c] = z*hold + (1.f - z)*hc;
                }
            }
        }
    }
}

// ---------------------------------------------------------------------------
// Projection: out = h1 @ Wp + bp ; fp32 xdec + fp32 d_out
// ---------------------------------------------------------------------------
__global__ __launch_bounds__(256) void proj(const float* __restrict__ h1,
                                            const float* __restrict__ Wp,
                                            const float* __restrict__ bp,
                                            float* __restrict__ xdec,
                                            float* __restrict__ out, int t){
    int row  = blockIdx.x * 4 + (threadIdx.x >> 6);
    int lane = threadIdx.x & 63;
    float v0 = h1[(size_t)row*128 + lane];
    float v1 = h1[(size_t)row*128 + 64 + lane];
    float w00 = Wp[lane*2+0],      w01 = Wp[lane*2+1];
    float w10 = Wp[(64+lane)*2+0], w11 = Wp[(64+lane)*2+1];
    float a0 = v0*w00 + v1*w10;
    float a1 = v0*w01 + v1*w11;
    #pragma unroll
    for (int off=32; off>0; off>>=1){
        a0 += __shfl_down(a0, off);
        a1 += __shfl_down(a1, off);
    }
    if (lane == 0){
        a0 += bp[0];
        a1 += bp[1];
        xdec[(size_t)row*2+0] = a0;
        xdec[(size_t)row*2+1] = a1;
        int b = row / N_, n = row % N_;
        size_t o = ((size_t)(b*T_ + t)*N_ + n)*2;
        out[o]   = a0;
        out[o+1] = a1;
    }
}

// ---------------------------------------------------------------------------
extern "C" void kernel_launch(void* const* d_in, const int* in_sizes, int n_in,
                              void* d_out, int out_size, void* d_ws, size_t ws_size,
                              hipStream_t stream){
    float* out = (float*)d_out;

    char* pb = (char*)d_ws;
    auto alloc = [&](size_t bytes)->void*{
        void* r = (void*)pb;
        pb += (bytes + 255) & ~(size_t)255;
        return r;
    };

    int* flag = (int*)alloc(16);
    sniff<<<1, 64, 0, stream>>>(d_in[2], flag);

    // fp32 copies of float inputs (skip targets idx 1) — one fused launch
    float* cw[21];
    const int idxs[20] = {0,2,3,4,5,6,7,8,9,10,11,12,13,14,15,16,17,18,19,20};
    CvtArgs ca;
    int maxn = 0;
    for (int ii = 0; ii < 20; ++ii){
        int i = idxs[ii];
        int n = in_sizes[i];
        cw[i] = (float*)alloc((size_t)n*4);
        ca.src[ii] = d_in[i];
        ca.dst[ii] = cw[i];
        ca.n[ii]   = n;
        if (n > maxn) maxn = n;
    }
    cvt_all<<<dim3((maxn+255)/256, 20), 256, 0, stream>>>(ca, flag);
    const float* src = cw[0];

    float* msq  = (float*)alloc((size_t)4*N_*N_*4);
    float* h0   = (float*)alloc((size_t)BN*H_*4);
    float* h1   = (float*)alloc((size_t)BN*H_*4);
    float* xdec = (float*)alloc((size_t)BN*DIN*4);
    u16*   asq  = (u16*)alloc((size_t)4*AROWS*DPITCH*2);

    // pre-transposed bf16 weights: Wt[Nout][KCpad]
    const int widx[8]  = {3,5,7,9,11,13,15,17};
    const int wKC[8]   = {650,650,1280,1280,650,650,1280,1280};
    const int wNout[8] = {256,128,256,128,256,128,256,128};
    u16* wt[8];
    for (int i=0;i<8;++i){
        int KCpad = (wKC[i] + 63) & ~63;
        wt[i] = (u16*)alloc((size_t)wNout[i]*KCpad*2);
        wtrans<<<dim3(KCpad/64, wNout[i]/64), 256, 0, stream>>>(cw[widx[i]], wt[i], wKC[i], wNout[i], KCpad);
    }

    // adaptive chunk: F + zr + Ft + slack
    size_t fixed = (size_t)(pb - (char*)d_ws);
    size_t perb  = (size_t)N_*1280*2 + (size_t)N_*256*4 + (size_t)256*DPITCH*2;
    int Bc = 64;
    while (Bc > 1 && fixed + (1<<20) + (size_t)Bc*perb > ws_size) Bc >>= 1;
    float* zr = (float*)alloc((size_t)Bc*N_*256*4);
    u16*   F  = (u16*)alloc((size_t)Bc*N_*1280*2);
    u16*   Ft = (u16*)alloc((size_t)Bc*256*DPITCH*2);
    alloc(1<<19);   // slack: OOB-row DMA reads stay inside the workspace

    {   // supports + squared supports, then bf16 row/col-padded copy
        dim3 g((N_+15)/16, (N_+15)/16, 2), b(16,16);
        support_prep<<<g, b, 0, stream>>>(cw[2], msq);
        int tot = 4*AROWS*DPITCH;
        asq_prep<<<dim3((tot+255)/256), 256, 0, stream>>>(msq, asq);
    }
    hipMemsetAsync(h0, 0, sizeof(float)*(size_t)BN*H_*2, stream);  // h0 and h1

    auto cell = [&](int layer, const float* x, long xbs, float* h,
                    const u16* Wg, const float* bg, const u16* Wc, const float* bc){
        int C      = layer ? 256 : 130;
        int KC     = 5*C;
        int KCpad  = (KC + 63) & ~63;
        int Din    = layer ? 128 : 2;
        int ctiles = (C + 63)/64;     // diffuse1 col tiles (3 | 4)
        int Cpad   = ctiles*64;
        for (int b0 = 0; b0 < B_; b0 += Bc){
            int rows = Bc*N_;
            int gy   = (rows + 127)/128;
            float* hb = h + (size_t)b0*N_*H_;
            // XCD-pinned 1-D grid sizes
            int T1 = Bc*ctiles, n1 = 8*12*((T1+7)/8);
            int T2 = Bc*2,      n2 = 8*12*((T2+7)/8);
            int ng0 = 8*((gy+7)/8)*2;     // gemm 128c tiles: gate ct=2
            int ng1 = 8*((gy+7)/8)*1;     // cand ct=1
            // P1: slot0 + transpose
            fill_t<<<dim3(DPITCH/64, Cpad/64, Bc), 256, 0, stream>>>(
                F, Ft, C, KC, Cpad, Din, b0, x, xbs, h);
            // P2: gate diffusion (all C cols)
            diffuse_mfma<<<dim3(n1), 256, 0, stream>>>(F, Ft, asq, C, KC, Cpad, 0, ctiles, T1);
            // P3: gate GEMM
            gemm_mfma<0><<<dim3(ng0), 256, 0, stream>>>(F, KC, rows, Wg, KCpad, bg, zr, (float*)nullptr, gy, 2);
            // P4: r*h into slot0 h-part + Ft h-rows
            rh_fill<<<dim3((rows*H_)/256), 256, 0, stream>>>(F, Ft, KC, Cpad, Din, b0, zr, h);
            // P5: candidate diffusion — only the 128 h-cols (x-cols reused from P2)
            diffuse_mfma<<<dim3(n2), 256, 0, stream>>>(F, Ft, asq, C, KC, Cpad, Din, 2, T2);
            // P6: candidate GEMM + GRU update
            gemm_mfma<1><<<dim3(ng1), 256, 0, stream>>>(F, KC, rows, Wc, KCpad, bc, zr, hb, gy, 1);
        }
    };

    // ---------------- encoder ----------------
    for (int t = 0; t < T_; ++t){
        cell(0, src + (size_t)t*N_*DIN, (long)T_*N_*DIN, h0, wt[0], cw[4], wt[1], cw[6]);
        cell(1, h0, (long)N_*H_, h1, wt[2], cw[8], wt[3], cw[10]);
    }

    // ---------------- decoder ----------------
    hipMemsetAsync(xdec, 0, sizeof(float)*(size_t)BN*DIN, stream);
    for (int t = 0; t < T_; ++t){
        cell(0, xdec, (long)N_*DIN, h0, wt[4], cw[12], wt[5], cw[14]);
        cell(1, h0, (long)N_*H_, h1, wt[6], cw[16], wt[7], cw[18]);
        proj<<<dim3(BN/4), 256, 0, stream>>>(h1, cw[19], cw[20], xdec, out, t);
    }
}

// Round 13
// 5918.982 us; speedup vs baseline: 1.2871x; 1.2871x over previous
//
#include <hip/hip_runtime.h>
#include <hip/hip_bf16.h>

#define B_  64
#define T_  12
#define N_  325
#define DIN 2
#define H_  128
#define BN  (B_*N_)    // 20800
#define DPITCH 384     // padded node pitch (k-extent)
#define AROWS 384      // padded m-rows per support matrix

typedef __hip_bfloat16 bf16;
typedef unsigned short u16;
typedef __attribute__((ext_vector_type(8))) short short8;
typedef __attribute__((ext_vector_type(4))) float f32x4;

__device__ __forceinline__ float b2f(bf16 v){ return __bfloat162float(v); }
__device__ __forceinline__ u16 f2b(float f){
    __hip_bfloat16 h = __float2bfloat16(f);
    return *reinterpret_cast<u16*>(&h);
}
__device__ __forceinline__ float ldf(const void* p, size_t i, int bf){
    return bf ? b2f(((const bf16*)p)[i]) : ((const float*)p)[i];
}

// async global->LDS, 16B per lane; dest = base + lane*16 (wave-uniform base)
__device__ __forceinline__ void gl_lds16(const u16* g, u16* l){
    __builtin_amdgcn_global_load_lds(
        (const __attribute__((address_space(1))) unsigned int*)g,
        (__attribute__((address_space(3))) unsigned int*)l, 16, 0, 0);
}

// ---------------------------------------------------------------------------
struct FillCfg { u16 *F, *Ft; const float *x, *h; long xbs; int C, KC, Cpad, Din, b0, nb; };
struct DiffCfg { u16* F; const u16* Ft; int C, KC, Cpad, coff, ctiles, T, nb; };
struct GemmCfg { const u16* Fb; const u16* Wt; const float* bias; float* zr; float* hb;
                 int KC, KCpad, rows, gy, ct, nb; };
struct RhCfg  { u16 *F, *Ft; const float *zr, *h; int KC, Cpad, Din, b0, total, nb; };

// ---------------------------------------------------------------------------
__global__ void sniff(const void* __restrict__ sup, int* __restrict__ flag){
    if (threadIdx.x == 0 && blockIdx.x == 0){
        float sb = 0.f, sf = 0.f;
        for (int n = 0; n < N_; ++n){
            sb += b2f(((const bf16*)sup)[n]);
            sf += ((const float*)sup)[n];
        }
        float db = fabsf(sb - 1.f), df = fabsf(sf - 1.f);
        *flag = (db < df) ? 1 : 0;
    }
}

struct CvtArgs { const void* src[12]; float* dst[12]; int n[12]; };

__global__ void cvt_all(CvtArgs a, const int* __restrict__ flag){
    int ii = blockIdx.y;
    int i  = blockIdx.x*256 + threadIdx.x;
    if (i >= a.n[ii]) return;
    a.dst[ii][i] = ldf(a.src[ii], i, *flag);
}

// ---------------------------------------------------------------------------
// msq[0]=S0, msq[1]=S0@S0, msq[2]=S1, msq[3]=S1@S1   (fp32, reads raw input)
// ---------------------------------------------------------------------------
__global__ void support_prep(const void* __restrict__ sup, const int* __restrict__ flag,
                             float* __restrict__ msq){
    int bf = *flag;
    int s = blockIdx.z;
    int m = blockIdx.y*16 + threadIdx.y;
    int n = blockIdx.x*16 + threadIdx.x;
    __shared__ float As[16][17], Bs[16][17];
    size_t base = (size_t)s*N_*N_;
    float acc = 0.f;
    for (int j0 = 0; j0 < N_; j0 += 16){
        As[threadIdx.y][threadIdx.x] = (m < N_ && j0+threadIdx.x < N_) ? ldf(sup, base + (size_t)m*N_ + j0+threadIdx.x, bf) : 0.f;
        Bs[threadIdx.y][threadIdx.x] = (j0+threadIdx.y < N_ && n < N_) ? ldf(sup, base + (size_t)(j0+threadIdx.y)*N_ + n, bf) : 0.f;
        __syncthreads();
        #pragma unroll
        for (int jj=0; jj<16; ++jj) acc += As[threadIdx.y][jj]*Bs[jj][threadIdx.x];
        __syncthreads();
    }
    if (m < N_ && n < N_){
        msq[(size_t)(2*s  )*N_*N_ + m*N_ + n] = ldf(sup, base + (size_t)m*N_ + n, bf);
        msq[(size_t)(2*s+1)*N_*N_ + m*N_ + n] = acc;
    }
}

__global__ void asq_prep(const float* __restrict__ msq, u16* __restrict__ asq){
    int idx = blockIdx.x*256 + threadIdx.x;
    int total = 4*AROWS*DPITCH;
    if (idx >= total) return;
    int col = idx % DPITCH;
    int rm  = idx / DPITCH;
    int m   = rm % AROWS;
    int k   = rm / AROWS;
    asq[idx] = (m < N_ && col < N_) ? f2b(msq[((size_t)k*N_ + m)*N_ + col]) : 0;
}

// ---------------------------------------------------------------------------
// Weight transpose (reads raw input, dtype per flag): W[KC][Nout] -> Wt[Nout][KCpad]
// ---------------------------------------------------------------------------
__global__ __launch_bounds__(256) void wtrans(const void* __restrict__ W, u16* __restrict__ Wt,
                                              int KC, int Nout, int KCpad,
                                              const int* __restrict__ flag){
    int bf = *flag;
    int k0 = blockIdx.x*64, c0 = blockIdx.y*64;
    int tid = threadIdx.x;
    __shared__ u16 T[64][72];
    #pragma unroll
    for (int it=0; it<2; ++it){
        int lin = it*256 + tid;
        int kl = lin >> 3, seg = lin & 7;
        int gk = k0 + kl, gc = c0 + seg*8;
        u16 tmp[8];
        #pragma unroll
        for (int e=0;e<8;++e) tmp[e] = (gk < KC) ? f2b(ldf(W, (size_t)gk*Nout + gc + e, bf)) : 0;
        *(uint4*)&T[kl][seg*8] = *(const uint4*)tmp;
    }
    __syncthreads();
    #pragma unroll
    for (int it=0; it<2; ++it){
        int lin = it*256 + tid;
        int cl = lin >> 3, seg = lin & 7;
        u16 tmp[8];
        #pragma unroll
        for (int j=0;j<8;++j) tmp[j] = T[seg*8+j][cl];
        *(uint4*)(Wt + (size_t)(c0+cl)*KCpad + k0 + seg*8) = *(const uint4*)tmp;
    }
}

// ---------------------------------------------------------------------------
// fill_k: F slot0 = [x|h] AND Ft = transpose. Dual-cfg merged grid.
// ---------------------------------------------------------------------------
__global__ __launch_bounds__(256) void fill_k(FillCfg ca, FillCfg cb, int na){
    int bi = blockIdx.x;
    FillCfg c = ca;
    if (bi >= na){ c = cb; bi -= na; }
    int gyc  = c.Cpad >> 6;
    int nblk = bi % 6;
    int rest = bi / 6;
    int cblk = rest % gyc;
    int bl   = rest / gyc;
    int bg = c.b0 + bl;
    int n0 = nblk*64, c0 = cblk*64;
    int tid = threadIdx.x;
    __shared__ u16 T[64][72];
    #pragma unroll
    for (int it=0; it<2; ++it){
        int lin = it*256 + tid;
        int nl = lin >> 3, seg = lin & 7;
        int gn = n0 + nl;
        u16 tmp[8];
        #pragma unroll
        for (int e=0;e<8;++e){
            int cc = c0 + seg*8 + e;
            float v = 0.f;
            if (gn < N_ && cc < c.C)
                v = (cc < c.Din) ? c.x[(size_t)bg*c.xbs + (size_t)gn*c.Din + cc]
                                 : c.h[((size_t)bg*N_ + gn)*H_ + (cc - c.Din)];
            tmp[e] = f2b(v);
        }
        *(uint4*)&T[nl][seg*8] = *(const uint4*)tmp;
        if (gn < N_){
            int cbase = c0 + seg*8;
            u16* dst = c.F + ((size_t)bl*N_ + gn)*c.KC + cbase;
            if (cbase + 7 < c.C){
                *(uint4*)dst = *(const uint4*)tmp;
            } else {
                #pragma unroll
                for (int e=0;e<8;++e) if (cbase + e < c.C) dst[e] = tmp[e];
            }
        }
    }
    __syncthreads();
    #pragma unroll
    for (int it=0; it<2; ++it){
        int lin = it*256 + tid;
        int cl = lin >> 3, seg = lin & 7;
        u16 tmp[8];
        #pragma unroll
        for (int j=0;j<8;++j) tmp[j] = T[seg*8+j][cl];
        *(uint4*)(c.Ft + (size_t)bl*c.Cpad*DPITCH + (size_t)(c0+cl)*DPITCH + n0 + seg*8)
            = *(const uint4*)tmp;
    }
}

// ---------------------------------------------------------------------------
// rh_k: F[slot0 h-part] = Ft[h-rows] = bf16(r * h). Dual-cfg merged grid.
// ---------------------------------------------------------------------------
__global__ void rh_k(RhCfg ca, RhCfg cb, int na){
    int blk = blockIdx.x;
    RhCfg c = ca;
    if (blk >= na){ c = cb; blk -= na; }
    int idx = blk*256 + threadIdx.x;
    if (idx >= c.total) return;
    int j   = idx & 127;
    int bnl = idx >> 7;
    int bl  = bnl / N_;
    int n   = bnl % N_;
    float r  = c.zr[(size_t)bnl*256 + 128 + j];
    float hv = c.h[((size_t)c.b0*N_ + bnl)*128 + j];
    u16 v = f2b(r * hv);
    c.F[(size_t)bnl*c.KC + c.Din + j] = v;
    c.Ft[((size_t)bl*c.Cpad + c.Din + j)*DPITCH + n] = v;
}

// ---------------------------------------------------------------------------
// diffuse_k: R11 hot loop (128m x 64c, async staging + swizzle, XCD-pinned
// decode). Dual-cfg merged grid (na is a multiple of 8 -> pinning preserved).
// ---------------------------------------------------------------------------
__global__ __launch_bounds__(256) void diffuse_k(DiffCfg ca, DiffCfg cb, int na,
                                                 const u16* __restrict__ asq){
    int bi = blockIdx.x;
    DiffCfg c = ca;
    if (bi >= na){ c = cb; bi -= na; }
    int xcd = bi & 7, m8 = bi >> 3;
    int tg = m8 / 12, s = m8 % 12;
    int t = tg*8 + xcd;
    if (t >= c.T) return;
    int bl = t / c.ctiles, cbk = t % c.ctiles;
    int y = s % 3, k = s / 3;

    const u16* A    = asq + (size_t)k*AROWS*DPITCH;
    const u16* Bt_g = c.Ft + ((size_t)bl*c.Cpad + c.coff)*DPITCH;
    u16*       Cm   = c.F + (size_t)bl*N_*c.KC + (size_t)(k+1)*c.C + c.coff;

    int m0 = y * 128;
    int c0 = cbk * 64;
    int tid = threadIdx.x;
    int wv = tid >> 6, lane = tid & 63, l15 = lane & 15, quad = lane >> 4;
    int lr = lane >> 3, ls = lane & 7;

    __shared__ u16 As[128*64];
    __shared__ u16 Bs[64*64];

    f32x4 acc[2][4];
    #pragma unroll
    for (int i2=0;i2<2;++i2)
        #pragma unroll
        for (int j=0;j<4;++j) acc[i2][j] = (f32x4){0.f,0.f,0.f,0.f};

    for (int k0 = 0; k0 < N_; k0 += 64){
        #pragma unroll
        for (int j=0;j<4;++j){
            int row = wv*32 + j*8 + lr;
            int seg = ls ^ lr;
            gl_lds16(A + (size_t)(m0+row)*DPITCH + k0 + seg*8, &As[(wv*32 + j*8)*64]);
        }
        #pragma unroll
        for (int j=0;j<2;++j){
            int row = wv*16 + j*8 + lr;
            int seg = ls ^ lr;
            gl_lds16(Bt_g + (size_t)(c0+row)*DPITCH + k0 + seg*8, &Bs[(wv*16 + j*8)*64]);
        }
        __syncthreads();
        #pragma unroll
        for (int ks = 0; ks < 64; ks += 32){
            int sw = (((ks>>3) + quad) ^ (l15 & 7)) << 3;
            short8 a0 = *(const short8*)&As[(wv*32      + l15)*64 + sw];
            short8 a1 = *(const short8*)&As[(wv*32 + 16 + l15)*64 + sw];
            short8 b0 = *(const short8*)&Bs[(     l15)*64 + sw];
            short8 b1 = *(const short8*)&Bs[(16 + l15)*64 + sw];
            short8 b2 = *(const short8*)&Bs[(32 + l15)*64 + sw];
            short8 b3 = *(const short8*)&Bs[(48 + l15)*64 + sw];
            acc[0][0] = __builtin_amdgcn_mfma_f32_16x16x32_bf16(a0,b0,acc[0][0],0,0,0);
            acc[0][1] = __builtin_amdgcn_mfma_f32_16x16x32_bf16(a0,b1,acc[0][1],0,0,0);
            acc[0][2] = __builtin_amdgcn_mfma_f32_16x16x32_bf16(a0,b2,acc[0][2],0,0,0);
            acc[0][3] = __builtin_amdgcn_mfma_f32_16x16x32_bf16(a0,b3,acc[0][3],0,0,0);
            acc[1][0] = __builtin_amdgcn_mfma_f32_16x16x32_bf16(a1,b0,acc[1][0],0,0,0);
            acc[1][1] = __builtin_amdgcn_mfma_f32_16x16x32_bf16(a1,b1,acc[1][1],0,0,0);
            acc[1][2] = __builtin_amdgcn_mfma_f32_16x16x32_bf16(a1,b2,acc[1][2],0,0,0);
            acc[1][3] = __builtin_amdgcn_mfma_f32_16x16x32_bf16(a1,b3,acc[1][3],0,0,0);
        }
        __syncthreads();
    }
    #pragma unroll
    for (int i2=0;i2<2;++i2){
        #pragma unroll
        for (int j=0;j<4;++j){
            int cc = c0 + j*16 + l15;
            #pragma unroll
            for (int r=0;r<4;++r){
                int m = m0 + wv*32 + i2*16 + quad*4 + r;
                if (m < N_ && c.coff + cc < c.C) Cm[(size_t)m*c.KC + cc] = f2b(acc[i2][j][r]);
            }
        }
    }
}

// ---------------------------------------------------------------------------
// gemm_k: R11 hot loop (128m x 64c, async staging + swizzle, XCD-pinned).
// Dual-cfg merged grid. MODE 0: zr = sigmoid. MODE 1: GRU update.
// ---------------------------------------------------------------------------
template<int MODE>
__global__ __launch_bounds__(256) void gemm_k(GemmCfg ca, GemmCfg cb, int na){
    int bi = blockIdx.x;
    GemmCfg c = ca;
    if (bi >= na){ c = cb; bi -= na; }
    int xcd = bi & 7, q = bi >> 3;
    int cbk = q % c.ct;
    int rt  = (q / c.ct)*8 + xcd;
    if (rt >= c.gy) return;
    int r0 = rt * 128;
    int c0 = cbk * 64;
    int tid = threadIdx.x;
    int wv = tid >> 6, lane = tid & 63, l15 = lane & 15, quad = lane >> 4;
    int lr = lane >> 3, ls = lane & 7;

    __shared__ u16 As[128*64];
    __shared__ u16 Bs[64*64];

    f32x4 acc[2][4];
    #pragma unroll
    for (int i2=0;i2<2;++i2)
        #pragma unroll
        for (int j=0;j<4;++j) acc[i2][j] = (f32x4){0.f,0.f,0.f,0.f};

    for (int k0 = 0; k0 < c.KCpad; k0 += 64){
        if (k0 + 64 <= c.KC){
            #pragma unroll
            for (int j=0;j<4;++j){
                int row = wv*32 + j*8 + lr;
                int seg = ls ^ lr;
                gl_lds16(c.Fb + (size_t)(r0+row)*c.KC + k0 + seg*8, &As[(wv*32 + j*8)*64]);
            }
        } else {
            #pragma unroll
            for (int it=0; it<4; ++it){
                int lin = it*256 + tid;
                int row = lin >> 3, sp = lin & 7;
                int seg = sp ^ (row & 7);
                int gr = r0 + row, gk = k0 + seg*8;
                u16 tmp[8];
                #pragma unroll
                for (int e=0;e<8;++e)
                    tmp[e] = (gk+e < c.KC) ? c.Fb[(size_t)gr*c.KC + gk+e] : (u16)0;
                *(uint4*)&As[row*64 + sp*8] = *(const uint4*)tmp;
            }
        }
        #pragma unroll
        for (int j=0;j<2;++j){
            int row = wv*16 + j*8 + lr;
            int seg = ls ^ lr;
            gl_lds16(c.Wt + (size_t)(c0+row)*c.KCpad + k0 + seg*8, &Bs[(wv*16 + j*8)*64]);
        }
        __syncthreads();
        #pragma unroll
        for (int ks = 0; ks < 64; ks += 32){
            int sw = (((ks>>3) + quad) ^ (l15 & 7)) << 3;
            short8 a0 = *(const short8*)&As[(wv*32      + l15)*64 + sw];
            short8 a1 = *(const short8*)&As[(wv*32 + 16 + l15)*64 + sw];
            short8 b0 = *(const short8*)&Bs[(     l15)*64 + sw];
            short8 b1 = *(const short8*)&Bs[(16 + l15)*64 + sw];
            short8 b2 = *(const short8*)&Bs[(32 + l15)*64 + sw];
            short8 b3 = *(const short8*)&Bs[(48 + l15)*64 + sw];
            acc[0][0] = __builtin_amdgcn_mfma_f32_16x16x32_bf16(a0,b0,acc[0][0],0,0,0);
            acc[0][1] = __builtin_amdgcn_mfma_f32_16x16x32_bf16(a0,b1,acc[0][1],0,0,0);
            acc[0][2] = __builtin_amdgcn_mfma_f32_16x16x32_bf16(a0,b2,acc[0][2],0,0,0);
            acc[0][3] = __builtin_amdgcn_mfma_f32_16x16x32_bf16(a0,b3,acc[0][3],0,0,0);
            acc[1][0] = __builtin_amdgcn_mfma_f32_16x16x32_bf16(a1,b0,acc[1][0],0,0,0);
            acc[1][1] = __builtin_amdgcn_mfma_f32_16x16x32_bf16(a1,b1,acc[1][1],0,0,0);
            acc[1][2] = __builtin_amdgcn_mfma_f32_16x16x32_bf16(a1,b2,acc[1][2],0,0,0);
            acc[1][3] = __builtin_amdgcn_mfma_f32_16x16x32_bf16(a1,b3,acc[1][3],0,0,0);
        }
        __syncthreads();
    }
    #pragma unroll
    for (int i2=0;i2<2;++i2){
        #pragma unroll
        for (int j=0;j<4;++j){
            int cc = c0 + j*16 + l15;
            #pragma unroll
            for (int r=0;r<4;++r){
                int gr = r0 + wv*32 + i2*16 + quad*4 + r;
                if (gr >= c.rows) continue;
                float v = acc[i2][j][r] + c.bias[cc];
                if (MODE == 0){
                    v = 1.f/(1.f + __expf(-v));
                    c.zr[(size_t)gr*256 + cc] = v;
                } else {
                    float hc   = tanhf(v);
                    float z    = c.zr[(size_t)gr*256 + cc];
                    float hold = c.hb[(size_t)gr*128 + cc];
                    c.hb[(size_t)gr*128 + cc] = z*hold + (1.f - z)*hc;
                }
            }
        }
    }
}

// ---------------------------------------------------------------------------
__global__ __launch_bounds__(256) void proj(const float* __restrict__ h1,
                                            const float* __restrict__ Wp,
                                            const float* __restrict__ bp,
                                            float* __restrict__ xdec,
                                            float* __restrict__ out, int t){
    int row  = blockIdx.x * 4 + (threadIdx.x >> 6);
    int lane = threadIdx.x & 63;
    float v0 = h1[(size_t)row*128 + lane];
    float v1 = h1[(size_t)row*128 + 64 + lane];
    float w00 = Wp[lane*2+0],      w01 = Wp[lane*2+1];
    float w10 = Wp[(64+lane)*2+0], w11 = Wp[(64+lane)*2+1];
    float a0 = v0*w00 + v1*w10;
    float a1 = v0*w01 + v1*w11;
    #pragma unroll
    for (int off=32; off>0; off>>=1){
        a0 += __shfl_down(a0, off);
        a1 += __shfl_down(a1, off);
    }
    if (lane == 0){
        a0 += bp[0];
        a1 += bp[1];
        xdec[(size_t)row*2+0] = a0;
        xdec[(size_t)row*2+1] = a1;
        int b = row / N_, n = row % N_;
        size_t o = ((size_t)(b*T_ + t)*N_ + n)*2;
        out[o]   = a0;
        out[o+1] = a1;
    }
}

// ---------------------------------------------------------------------------
struct Layer {
    u16 *F, *Ft; float *zr; float *h;
    const u16 *Wg, *Wc; const float *bg, *bc;
    int C, KC, KCpad, Din, ctiles, Cpad;
};

extern "C" void kernel_launch(void* const* d_in, const int* in_sizes, int n_in,
                              void* d_out, int out_size, void* d_ws, size_t ws_size,
                              hipStream_t stream){
    float* out = (float*)d_out;

    char* pb = (char*)d_ws;
    auto alloc = [&](size_t bytes)->void*{
        void* r = (void*)pb;
        pb += (bytes + 255) & ~(size_t)255;
        return r;
    };

    int* flag = (int*)alloc(16);
    sniff<<<1, 64, 0, stream>>>(d_in[2], flag);

    // fp32 copies: src, biases, Wp, bp (weights/supports read raw by prep kernels)
    const int idxs[11] = {0,4,6,8,10,12,14,16,18,19,20};
    float* cw[21] = {nullptr};
    CvtArgs ca;
    int maxn = 0;
    for (int ii = 0; ii < 11; ++ii){
        int i = idxs[ii];
        int n = in_sizes[i];
        cw[i] = (float*)alloc((size_t)n*4);
        ca.src[ii] = d_in[i];
        ca.dst[ii] = cw[i];
        ca.n[ii]   = n;
        if (n > maxn) maxn = n;
    }
    cvt_all<<<dim3((maxn+255)/256, 11), 256, 0, stream>>>(ca, flag);
    const float* src = cw[0];

    float* msq  = (float*)alloc((size_t)4*N_*N_*4);
    float* h0   = (float*)alloc((size_t)BN*H_*4);
    float* h1   = (float*)alloc((size_t)BN*H_*4);
    float* xdec = (float*)alloc((size_t)BN*DIN*4);
    u16*   asq  = (u16*)alloc((size_t)4*AROWS*DPITCH*2);

    const int widx[8]  = {3,5,7,9,11,13,15,17};
    const int wKC[8]   = {650,650,1280,1280,650,650,1280,1280};
    const int wNout[8] = {256,128,256,128,256,128,256,128};
    u16* wt[8];
    for (int i=0;i<8;++i){
        int KCpad = (wKC[i] + 63) & ~63;
        wt[i] = (u16*)alloc((size_t)wNout[i]*KCpad*2);
        wtrans<<<dim3(KCpad/64, wNout[i]/64), 256, 0, stream>>>(d_in[widx[i]], wt[i], wKC[i], wNout[i], KCpad, flag);
    }

    {   // supports + squares, bf16 padded copy
        dim3 g((N_+15)/16, (N_+15)/16, 2), b(16,16);
        support_prep<<<g, b, 0, stream>>>(d_in[2], flag, msq);
        int tot = 4*AROWS*DPITCH;
        asq_prep<<<dim3((tot+255)/256), 256, 0, stream>>>(msq, asq);
    }
    hipMemsetAsync(h0, 0, sizeof(float)*(size_t)BN*H_*2, stream);  // h0 and h1

    // ---- buffer sets: dual (layer-pipelined encoder) if ws allows ----
    size_t fixed = (size_t)(pb - (char*)d_ws);
    size_t need0 = (size_t)BN*256*4 + (size_t)BN*650*2  + (size_t)B_*192*DPITCH*2;
    size_t need1 = (size_t)BN*256*4 + (size_t)BN*1280*2 + (size_t)B_*256*DPITCH*2;
    bool dual = (fixed + need0 + need1 + (4<<20)) <= ws_size;

    // helpers -----------------------------------------------------------
    auto mkFill = [&](Layer& L, const float* x, long xbs, int b0, int Bc)->FillCfg{
        return FillCfg{L.F, L.Ft, x, L.h, xbs, L.C, L.KC, L.Cpad, L.Din, b0,
                       6*(L.Cpad/64)*Bc};
    };
    auto mkD1 = [&](Layer& L, int Bc)->DiffCfg{
        int T = Bc*L.ctiles;
        return DiffCfg{L.F, L.Ft, L.C, L.KC, L.Cpad, 0, L.ctiles, T, 12*(((T+7)/8)*8)};
    };
    auto mkD2 = [&](Layer& L, int Bc)->DiffCfg{
        int T = Bc*2;
        return DiffCfg{L.F, L.Ft, L.C, L.KC, L.Cpad, L.Din, 2, T, 12*(((T+7)/8)*8)};
    };
    auto mkG0 = [&](Layer& L, int b0, int Bc)->GemmCfg{
        int rows = Bc*N_, gy = (rows+127)/128;
        return GemmCfg{L.F, L.Wg, L.bg, L.zr, L.h + (size_t)b0*N_*H_,
                       L.KC, L.KCpad, rows, gy, 4, 8*((gy+7)/8)*4};
    };
    auto mkG1 = [&](Layer& L, int b0, int Bc)->GemmCfg{
        int rows = Bc*N_, gy = (rows+127)/128;
        return GemmCfg{L.F, L.Wc, L.bc, L.zr, L.h + (size_t)b0*N_*H_,
                       L.KC, L.KCpad, rows, gy, 2, 8*((gy+7)/8)*2};
    };
    auto mkRh = [&](Layer& L, int b0, int Bc)->RhCfg{
        int total = Bc*N_*H_;
        return RhCfg{L.F, L.Ft, L.zr, L.h, L.KC, L.Cpad, L.Din, b0, total, (total+255)/256};
    };
    auto runCellSeq = [&](Layer& L, const float* x, long xbs, int b0, int Bc){
        FillCfg f = mkFill(L, x, xbs, b0, Bc);
        fill_k<<<dim3(f.nb), 256, 0, stream>>>(f, f, f.nb);
        DiffCfg d1 = mkD1(L, Bc);
        diffuse_k<<<dim3(d1.nb), 256, 0, stream>>>(d1, d1, d1.nb, asq);
        GemmCfg g0 = mkG0(L, b0, Bc);
        gemm_k<0><<<dim3(g0.nb), 256, 0, stream>>>(g0, g0, g0.nb);
        RhCfg r = mkRh(L, b0, Bc);
        rh_k<<<dim3(r.nb), 256, 0, stream>>>(r, r, r.nb);
        DiffCfg d2 = mkD2(L, Bc);
        diffuse_k<<<dim3(d2.nb), 256, 0, stream>>>(d2, d2, d2.nb, asq);
        GemmCfg g1 = mkG1(L, b0, Bc);
        gemm_k<1><<<dim3(g1.nb), 256, 0, stream>>>(g1, g1, g1.nb);
    };

    if (dual){
        float* zr0 = (float*)alloc((size_t)BN*256*4);
        u16*   F0  = (u16*)alloc((size_t)BN*650*2);
        u16*   Ft0 = (u16*)alloc((size_t)B_*192*DPITCH*2);
        float* zr1 = (float*)alloc((size_t)BN*256*4);
        u16*   F1  = (u16*)alloc((size_t)BN*1280*2);
        u16*   Ft1 = (u16*)alloc((size_t)B_*256*DPITCH*2);
        alloc(1<<19);  // slack for OOB-row DMA

        Layer E0{F0, Ft0, zr0, h0, wt[0], wt[1], cw[4],  cw[6],  130, 650, 704, 2,   3, 192};
        Layer E1{F1, Ft1, zr1, h1, wt[2], wt[3], cw[8],  cw[10], 256, 1280,1280,128, 4, 256};
        Layer D0{F0, Ft0, zr0, h0, wt[4], wt[5], cw[12], cw[14], 130, 650, 704, 2,   3, 192};
        Layer D1{F1, Ft1, zr1, h1, wt[6], wt[7], cw[16], cw[18], 256, 1280,1280,128, 4, 256};

        // ------- encoder: layer-pipelined super-steps -------
        for (int s = 0; s <= T_; ++s){
            bool has0 = (s < T_), has1 = (s >= 1);
            const float* x0 = src + (size_t)s*N_*DIN;
            FillCfg f0 = mkFill(E0, x0, (long)T_*N_*DIN, 0, B_);
            FillCfg f1 = mkFill(E1, h0, (long)N_*H_,     0, B_);
            if (has0 && has1) fill_k<<<dim3(f0.nb+f1.nb),256,0,stream>>>(f0, f1, f0.nb);
            else if (has0)    fill_k<<<dim3(f0.nb),256,0,stream>>>(f0, f0, f0.nb);
            else              fill_k<<<dim3(f1.nb),256,0,stream>>>(f1, f1, f1.nb);

            DiffCfg a1 = mkD1(E0, B_), b1 = mkD1(E1, B_);
            if (has0 && has1) diffuse_k<<<dim3(a1.nb+b1.nb),256,0,stream>>>(a1, b1, a1.nb, asq);
            else if (has0)    diffuse_k<<<dim3(a1.nb),256,0,stream>>>(a1, a1, a1.nb, asq);
            else              diffuse_k<<<dim3(b1.nb),256,0,stream>>>(b1, b1, b1.nb, asq);

            GemmCfg ga = mkG0(E0, 0, B_), gb = mkG0(E1, 0, B_);
            if (has0 && has1) gemm_k<0><<<dim3(ga.nb+gb.nb),256,0,stream>>>(ga, gb, ga.nb);
            else if (has0)    gemm_k<0><<<dim3(ga.nb),256,0,stream>>>(ga, ga, ga.nb);
            else              gemm_k<0><<<dim3(gb.nb),256,0,stream>>>(gb, gb, gb.nb);

            RhCfg ra = mkRh(E0, 0, B_), rb = mkRh(E1, 0, B_);
            if (has0 && has1) rh_k<<<dim3(ra.nb+rb.nb),256,0,stream>>>(ra, rb, ra.nb);
            else if (has0)    rh_k<<<dim3(ra.nb),256,0,stream>>>(ra, ra, ra.nb);
            else              rh_k<<<dim3(rb.nb),256,0,stream>>>(rb, rb, rb.nb);

            DiffCfg a2 = mkD2(E0, B_), b2 = mkD2(E1, B_);
            if (has0 && has1) diffuse_k<<<dim3(a2.nb+b2.nb),256,0,stream>>>(a2, b2, a2.nb, asq);
            else if (has0)    diffuse_k<<<dim3(a2.nb),256,0,stream>>>(a2, a2, a2.nb, asq);
            else              diffuse_k<<<dim3(b2.nb),256,0,stream>>>(b2, b2, b2.nb, asq);

            GemmCfg ha = mkG1(E0, 0, B_), hb = mkG1(E1, 0, B_);
            if (has0 && has1) gemm_k<1><<<dim3(ha.nb+hb.nb),256,0,stream>>>(ha, hb, ha.nb);
            else if (has0)    gemm_k<1><<<dim3(ha.nb),256,0,stream>>>(ha, ha, ha.nb);
            else              gemm_k<1><<<dim3(hb.nb),256,0,stream>>>(hb, hb, hb.nb);
        }

        // ------- decoder: serial (proj feedback) -------
        hipMemsetAsync(xdec, 0, sizeof(float)*(size_t)BN*DIN, stream);
        for (int t = 0; t < T_; ++t){
            runCellSeq(D0, xdec, (long)N_*DIN, 0, B_);
            runCellSeq(D1, h0,   (long)N_*H_,  0, B_);
            proj<<<dim3(BN/4), 256, 0, stream>>>(h1, cw[19], cw[20], xdec, out, t);
        }
    } else {
        // ------- fallback: R11 sequential with adaptive chunking -------
        size_t perb = (size_t)N_*1280*2 + (size_t)N_*256*4 + (size_t)256*DPITCH*2;
        int Bc = 64;
        while (Bc > 2 && fixed + (1<<20) + (size_t)Bc*perb > ws_size) Bc >>= 1;
        float* zr = (float*)alloc((size_t)Bc*N_*256*4);
        u16*   F  = (u16*)alloc((size_t)Bc*N_*1280*2);
        u16*   Ft = (u16*)alloc((size_t)Bc*256*DPITCH*2);
        alloc(1<<19);

        Layer SE0{F, Ft, zr, h0, wt[0], wt[1], cw[4],  cw[6],  130, 650, 704, 2,   3, 192};
        Layer SE1{F, Ft, zr, h1, wt[2], wt[3], cw[8],  cw[10], 256, 1280,1280,128, 4, 256};
        Layer SD0{F, Ft, zr, h0, wt[4], wt[5], cw[12], cw[14], 130, 650, 704, 2,   3, 192};
        Layer SD1{F, Ft, zr, h1, wt[6], wt[7], cw[16], cw[18], 256, 1280,1280,128, 4, 256};

        for (int t = 0; t < T_; ++t){
            for (int b0 = 0; b0 < B_; b0 += Bc)
                runCellSeq(SE0, src + (size_t)t*N_*DIN, (long)T_*N_*DIN, b0, Bc);
            for (int b0 = 0; b0 < B_; b0 += Bc)
                runCellSeq(SE1, h0, (long)N_*H_, b0, Bc);
        }
        hipMemsetAsync(xdec, 0, sizeof(float)*(size_t)BN*DIN, stream);
        for (int t = 0; t < T_; ++t){
            for (int b0 = 0; b0 < B_; b0 += Bc)
                runCellSeq(SD0, xdec, (long)N_*DIN, b0, Bc);
            for (int b0 = 0; b0 < B_; b0 += Bc)
                runCellSeq(SD1, h0, (long)N_*H_, b0, Bc);
            proj<<<dim3(BN/4), 256, 0, stream>>>(h1, cw[19], cw[20], xdec, out, t);
        }
    }
}